// Round 12
// baseline (7658.856 us; speedup 1.0000x reference)
//
#include <hip/hip_runtime.h>
#include <hip/hip_fp16.h>

#define BB 32
#define LL 512
#define HH 1024
#define NL 4
#define TPL 32   // blocks per layer
#define CPB 32   // cols per block
#define TAGM 0x0001000100010001ULL   // LSB of each f16 in an 8B quantum

typedef unsigned long long ull;
typedef _Float16 f16x8 __attribute__((ext_vector_type(8)));
typedef float    f32x4 __attribute__((ext_vector_type(4)));

__device__ __forceinline__ f16x8 cvt8(const float* __restrict__ p) {
  f32x4 lo = *reinterpret_cast<const f32x4*>(p);
  f32x4 hi = *reinterpret_cast<const f32x4*>(p + 4);
  f16x8 r;
#pragma unroll
  for (int e = 0; e < 4; ++e) { r[e] = (_Float16)lo[e]; r[e + 4] = (_Float16)hi[e]; }
  return r;
}

// Fast tier: plain cacheable 16B loads. With never-reused slot addresses the
// first touch per XCD is a COLD L2 miss -> fetches fresh post-flag data from
// MALL and caches it for the other ~31 same-XCD blocks (line dedup). Tags
// (inverted parity: 0xAA poison is always invalid) catch anything exotic.
__device__ __forceinline__ bool try_plain_row16(f16x8* __restrict__ o,
                                                const _Float16* __restrict__ base,
                                                ull wantv) {
  f16x8 tmp[16];
#pragma unroll
  for (int j = 0; j < 16; ++j)
    tmp[j] = *reinterpret_cast<const f16x8*>(base + j * 32);
  ull bad = 0;
#pragma unroll
  for (int j = 0; j < 16; ++j) {
    union { f16x8 v; ull u[2]; } c; c.v = tmp[j];
    bad |= ((c.u[0] ^ wantv) | (c.u[1] ^ wantv)) & TAGM;
  }
  if (bad) return false;
#pragma unroll
  for (int j = 0; j < 16; ++j) o[j] = tmp[j];
  return true;
}

// Safety net (round-6-proven): 8B relaxed agent atomic spin at the MALL.
__device__ __forceinline__ void spin_load_row16(f16x8* __restrict__ o,
                                                const _Float16* __restrict__ base,
                                                ull wantv) {
  const ull* p = reinterpret_cast<const ull*>(base);
  ull q0[16], q1[16];
#pragma unroll
  for (int j = 0; j < 16; ++j) {
    q0[j] = __hip_atomic_load(p + j * 8,     __ATOMIC_RELAXED, __HIP_MEMORY_SCOPE_AGENT);
    q1[j] = __hip_atomic_load(p + j * 8 + 1, __ATOMIC_RELAXED, __HIP_MEMORY_SCOPE_AGENT);
  }
  for (;;) {
    ull bad = 0;
#pragma unroll
    for (int j = 0; j < 16; ++j)
      bad |= ((q0[j] ^ wantv) | (q1[j] ^ wantv)) & TAGM;
    if (bad == 0) break;
#pragma unroll
    for (int j = 0; j < 16; ++j) {
      q0[j] = __hip_atomic_load(p + j * 8,     __ATOMIC_RELAXED, __HIP_MEMORY_SCOPE_AGENT);
      q1[j] = __hip_atomic_load(p + j * 8 + 1, __ATOMIC_RELAXED, __HIP_MEMORY_SCOPE_AGENT);
    }
  }
#pragma unroll
  for (int j = 0; j < 16; ++j) {
    union { ull u[2]; f16x8 v; } c;
    c.u[0] = q0[j]; c.u[1] = q1[j];
    o[j] = c.v;
  }
}

__device__ __forceinline__ void load_row16(f16x8* __restrict__ o,
                                           const _Float16* __restrict__ base,
                                           ull wantv) {
  if (try_plain_row16(o, base, wantv)) return;
  spin_load_row16(o, base, wantv);
}

// Persistent pipeline, 128 active blocks: layer = blockIdx&7 (XCD-locality
// heuristic only; flag gates + tags + MALL fallback keep correctness
// placement-independent). Block: 32 cols, weights in VGPRs; waves 0-1 input
// GEMM, waves 2-3 hidden GEMM. h transport: atomic stores to MALL, then
// flag-gated plain 16B loads of never-reused addresses (cold-miss dedup).
__global__ __launch_bounds__(256, 1) void rnn_persist(
    const float* __restrict__ x,   // [B][L][H] f32
    const float* __restrict__ h0,  // [NL][B][H] f32
    const float* __restrict__ WI,  // [NL][H][H] f32
    const float* __restrict__ BI,  // [NL][H]
    const float* __restrict__ WH,  // [NL][H][H] f32
    const float* __restrict__ BH,  // [NL][H]
    float* __restrict__ out,       // [B][L][H] f32 ++ hfinal [NL][B][H]
    _Float16* __restrict__ hbuf,   // [NL][RS][B][H] f16 (tagged), RS runtime
    unsigned* __restrict__ pflag,  // [NL][TPL]: t+1 after step t
    int rsmask, int rshift) {      // RS-1, log2(RS)
  const int l = blockIdx.x & 7;
  if (l >= NL) return;
  const int tile = blockIdx.x >> 3;
  const int c0   = tile * CPB;
  const int tid  = threadIdx.x;
  const int w    = tid >> 6;
  const int lane = tid & 63;
  const int crow = lane & 15;
  const int kgrp = lane >> 4;
  const int kofs = (w & 1) * 512;

  // ---- weight fragments -> registers (once) ----
  f16x8 wfrag[2][16];
  {
    const float* Wb = (w < 2 ? WI : WH) + (size_t)l * HH * HH;
#pragma unroll
    for (int ct = 0; ct < 2; ++ct) {
      const float* wr = Wb + (size_t)(c0 + ct * 16 + crow) * HH + kofs + kgrp * 8;
#pragma unroll
      for (int j = 0; j < 16; ++j) wfrag[ct][j] = cvt8(wr + j * 32);
    }
  }

  // ---- epilogue: tid<128 -> (row rb2, 8 cols at c8) ----
  const int rb2 = tid >> 2;
  const int c8  = (tid & 3) * 8;
  float bias8[8];
#pragma unroll
  for (int j = 0; j < 8; ++j)
    bias8[j] = BI[l * HH + c0 + c8 + j] + BH[l * HH + c0 + c8 + j];

  __shared__ float red[2][4][2][16][34];

  for (int t = 0; t < LL; ++t) {
    // tag bit = parity ^ 1 so 0xAA/0x00 poison never validates
    const ull wantI = (((t >> rshift) & 1) ^ 1) ? TAGM : 0ULL;        // gen t
    const ull wantH = ((((t - 1) >> rshift) & 1) ^ 1) ? TAGM : 0ULL;  // gen t-1

    // ---------- flag gates (round-8/11-proven) ----------
    if (tid < 96) {
      const int g  = tid >> 5;
      const int Lt = tid & 31;
      if (g == 0) {
        if (t > 0)
          while (__hip_atomic_load(&pflag[l * TPL + Lt], __ATOMIC_RELAXED,
                                   __HIP_MEMORY_SCOPE_AGENT) < (unsigned)t)
            __builtin_amdgcn_s_sleep(2);
      } else if (g == 1) {
        if (l > 0)
          while (__hip_atomic_load(&pflag[(l - 1) * TPL + Lt], __ATOMIC_RELAXED,
                                   __HIP_MEMORY_SCOPE_AGENT) < (unsigned)(t + 1))
            __builtin_amdgcn_s_sleep(2);
      } else {
        if (l < NL - 1 && t > rsmask)   // WAR (only if ring actually reuses)
          while (__hip_atomic_load(&pflag[(l + 1) * TPL + Lt], __ATOMIC_RELAXED,
                                   __HIP_MEMORY_SCOPE_AGENT) < (unsigned)(t - rsmask))
            __builtin_amdgcn_s_sleep(2);
      }
    }
    __syncthreads();

    // ---------- phased operand load + MFMA ----------
    f32x4 acc[2][2];
#pragma unroll
    for (int ct = 0; ct < 2; ++ct)
#pragma unroll
      for (int rt = 0; rt < 2; ++rt) acc[ct][rt] = (f32x4){0.f, 0.f, 0.f, 0.f};

#pragma unroll
    for (int rt = 0; rt < 2; ++rt) {
      f16x8 af[16];
      const size_t rowoff = (size_t)(rt * 16 + crow) * HH + kofs + kgrp * 8;
      if (w < 2) {            // input operand: x (l==0) or h_{l-1} gen t
        if (l == 0) {
          const float* r = x + ((size_t)(rt * 16 + crow) * LL + t) * HH + kofs + kgrp * 8;
#pragma unroll
          for (int j = 0; j < 16; ++j) af[j] = cvt8(r + j * 32);
        } else {
          const size_t slot = ((size_t)(l - 1) * (rsmask + 1) + (t & rsmask)) * BB * HH;
          load_row16(af, hbuf + slot + rowoff, wantI);
        }
      } else {                // hidden operand: h0 (t==0) or own h gen t-1
        if (t == 0) {
          const float* r = h0 + ((size_t)l * BB + rt * 16 + crow) * HH + kofs + kgrp * 8;
#pragma unroll
          for (int j = 0; j < 16; ++j) af[j] = cvt8(r + j * 32);
        } else {
          const size_t slot = ((size_t)l * (rsmask + 1) + ((t - 1) & rsmask)) * BB * HH;
          load_row16(af, hbuf + slot + rowoff, wantH);
        }
      }
#pragma unroll
      for (int j = 0; j < 16; ++j)
#pragma unroll
        for (int ct = 0; ct < 2; ++ct)
          acc[ct][rt] = __builtin_amdgcn_mfma_f32_16x16x32_f16(af[j], wfrag[ct][j],
                                                               acc[ct][rt], 0, 0, 0);
    }

    // ---------- cross-wave k-reduce via LDS (ping-pong) ----------
    const int pp = t & 1;
#pragma unroll
    for (int ct = 0; ct < 2; ++ct)
#pragma unroll
      for (int rt = 0; rt < 2; ++rt)
#pragma unroll
        for (int r = 0; r < 4; ++r)
          red[pp][w][rt][kgrp * 4 + r][ct * 16 + crow] = acc[ct][rt][r];
    __syncthreads();

    float v[8];
    if (tid < 128) {
#pragma unroll
      for (int j = 0; j < 8; ++j) {
        float s = bias8[j];
#pragma unroll
        for (int w2 = 0; w2 < 4; ++w2) s += red[pp][w2][rb2 >> 4][rb2 & 15][c8 + j];
        v[j] = tanhf(s);
      }
      union { _Float16 h[8]; ull u[2]; } pk;
#pragma unroll
      for (int j = 0; j < 8; ++j) pk.h[j] = (_Float16)v[j];
      const ull tg = (((t >> rshift) & 1) ^ 1) ? TAGM : 0ULL;
      pk.u[0] = (pk.u[0] & ~TAGM) | tg;
      pk.u[1] = (pk.u[1] & ~TAGM) | tg;
      const size_t off =
          ((size_t)l * (rsmask + 1) + (t & rsmask)) * BB * HH + (size_t)rb2 * HH + c0 + c8;
      __hip_atomic_store(reinterpret_cast<ull*>(hbuf + off), pk.u[0],
                         __ATOMIC_RELAXED, __HIP_MEMORY_SCOPE_AGENT);
      __hip_atomic_store(reinterpret_cast<ull*>(hbuf + off) + 1, pk.u[1],
                         __ATOMIC_RELAXED, __HIP_MEMORY_SCOPE_AGENT);
    }
    // Drain: all waves wait vmcnt(0) entering the barrier -> h at MALL.
    __syncthreads();

    // ---------- publish progress ----------
    if (tid == 0)
      __hip_atomic_store(&pflag[l * TPL + tile], (unsigned)(t + 1), __ATOMIC_RELAXED,
                         __HIP_MEMORY_SCOPE_AGENT);

    // ---------- out stores (off critical path) ----------
    if (tid < 128) {
      if (l == NL - 1) {
        f32x4 o0 = {v[0], v[1], v[2], v[3]}, o1 = {v[4], v[5], v[6], v[7]};
        float* po = out + ((size_t)rb2 * LL + t) * HH + c0 + c8;
        __builtin_nontemporal_store(o0, reinterpret_cast<f32x4*>(po));
        __builtin_nontemporal_store(o1, reinterpret_cast<f32x4*>(po + 4));
      }
      if (t == LL - 1) {
        f32x4 o0 = {v[0], v[1], v[2], v[3]}, o1 = {v[4], v[5], v[6], v[7]};
        float* pf = out + (size_t)BB * LL * HH + ((size_t)l * BB + rb2) * HH + c0 + c8;
        __builtin_nontemporal_store(o0, reinterpret_cast<f32x4*>(pf));
        __builtin_nontemporal_store(o1, reinterpret_cast<f32x4*>(pf + 4));
      }
    }
  }
}

extern "C" void kernel_launch(void* const* d_in, const int* in_sizes, int n_in,
                              void* d_out, int out_size, void* d_ws, size_t ws_size,
                              hipStream_t stream) {
  const float* x  = (const float*)d_in[0];
  const float* h0 = (const float*)d_in[1];
  const float* WI = (const float*)d_in[2];
  const float* BI = (const float*)d_in[3];
  const float* WH = (const float*)d_in[4];
  const float* BH = (const float*)d_in[5];
  float* out = (float*)d_out;

  // Choose RS (slots per layer) to fit ws: RS=512 = fully non-reused h.
  const size_t perSlot = (size_t)NL * BB * HH * sizeof(_Float16);  // 256 KB
  int rs = 512;
  while (rs > 8 && (size_t)rs * perSlot + 65536 > ws_size) rs >>= 1;
  int rshift = 0;
  while ((1 << rshift) < rs) ++rshift;

  _Float16* hbuf = (_Float16*)d_ws;
  unsigned* pflag = (unsigned*)((char*)d_ws + (size_t)rs * perSlot);

  // NO hbuf memset: never-touched addresses guarantee cold L2 misses (dedup
  // path); flag gates guarantee the data is at MALL before any read.
  hipMemsetAsync(pflag, 0, (size_t)NL * TPL * sizeof(unsigned), stream);
  rnn_persist<<<256, 256, 0, stream>>>(x, h0, WI, BI, WH, BH, out, hbuf, pflag,
                                       rs - 1, rshift);
}

// Round 13
// 6590.962 us; speedup vs baseline: 1.1620x; 1.1620x over previous
//
#include <hip/hip_runtime.h>
#include <hip/hip_fp16.h>

#define BB 32
#define LL 512
#define HH 1024
#define NL 4
#define TPL 32   // blocks per layer
#define CPB 32   // cols per block
#define TAGM 0x0001000100010001ULL   // LSB of each f16 in an 8B quantum
#define SROW 1032  // LDS row stride in f16: 2064B = 16B-aligned, banks spread

typedef unsigned long long ull;
typedef _Float16 f16x8 __attribute__((ext_vector_type(8)));
typedef float    f32x4 __attribute__((ext_vector_type(4)));

__device__ __forceinline__ f16x8 cvt8(const float* __restrict__ p) {
  f32x4 lo = *reinterpret_cast<const f32x4*>(p);
  f32x4 hi = *reinterpret_cast<const f32x4*>(p + 4);
  f16x8 r;
#pragma unroll
  for (int e = 0; e < 4; ++e) { r[e] = (_Float16)lo[e]; r[e + 4] = (_Float16)hi[e]; }
  return r;
}

// Stage one 16B quantum global->LDS: coalesced plain load (8 lanes share a
// 128B line -> line-dedup'd in the XCD L2), tag-validated; fallback is the
// round-6-proven 8B relaxed agent atomic spin at the MALL (always terminates).
__device__ __forceinline__ void stage_q(_Float16* __restrict__ sdst,
                                        const _Float16* __restrict__ gsrc,
                                        ull want) {
  union { f16x8 v; ull u[2]; } c;
  c.v = *reinterpret_cast<const f16x8*>(gsrc);
  if ((((c.u[0] ^ want) | (c.u[1] ^ want)) & TAGM) != 0) {
    const ull* p = reinterpret_cast<const ull*>(gsrc);
    do {
      c.u[0] = __hip_atomic_load(p, __ATOMIC_RELAXED, __HIP_MEMORY_SCOPE_AGENT);
    } while ((c.u[0] ^ want) & TAGM);
    do {
      c.u[1] = __hip_atomic_load(p + 1, __ATOMIC_RELAXED, __HIP_MEMORY_SCOPE_AGENT);
    } while ((c.u[1] ^ want) & TAGM);
  }
  *reinterpret_cast<f16x8*>(sdst) = c.v;
}

// Persistent pipeline, 128 active blocks: layer = blockIdx&7 (XCD-locality
// heuristic only; flag gates + tags + MALL fallback keep correctness
// placement-independent). Block: 32 cols; weights in VGPRs (each wave holds
// BOTH matrices' k-quarter). h transport: atomic stores to MALL; flag-gated
// COALESCED 16B staged reads into LDS (8x fewer line transactions than the
// strided per-lane pattern of rounds 1-12), MFMA fragments from LDS.
__global__ __launch_bounds__(256, 1) void rnn_persist(
    const float* __restrict__ x,   // [B][L][H] f32
    const float* __restrict__ h0,  // [NL][B][H] f32
    const float* __restrict__ WI,  // [NL][H][H] f32
    const float* __restrict__ BI,  // [NL][H]
    const float* __restrict__ WH,  // [NL][H][H] f32
    const float* __restrict__ BH,  // [NL][H]
    float* __restrict__ out,       // [B][L][H] f32 ++ hfinal [NL][B][H]
    _Float16* __restrict__ hbuf,   // [NL][RS][B][H] f16 (tagged), RS runtime
    unsigned* __restrict__ pflag,  // [NL][TPL]: t+1 after step t
    int rsmask, int rshift) {
  const int l = blockIdx.x & 7;
  if (l >= NL) return;
  const int tile = blockIdx.x >> 3;
  const int c0   = tile * CPB;
  const int tid  = threadIdx.x;
  const int w    = tid >> 6;          // wave -> k-quarter [256w, 256w+256)
  const int lane = tid & 63;
  const int crow = lane & 15;
  const int kgrp = lane >> 4;

  extern __shared__ char smem[];
  _Float16* sIn  = (_Float16*)smem;                     // [32][SROW]
  _Float16* sHid = sIn + 32 * SROW;                     // [32][SROW]
  float*    redp = (float*)(sHid + 32 * SROW);          // [4][2][16][34]
#define RED(W, RT, R, C) redp[((((W)*2 + (RT)) * 16 + (R)) * 34) + (C)]

  // ---- weight fragments -> registers (once): both matrices, own k-quarter ----
  f16x8 wIf[2][8], wHf[2][8];
  {
    const float* WIb = WI + (size_t)l * HH * HH;
    const float* WHb = WH + (size_t)l * HH * HH;
#pragma unroll
    for (int ct = 0; ct < 2; ++ct) {
      const size_t row = (size_t)(c0 + ct * 16 + crow) * HH;
#pragma unroll
      for (int j = 0; j < 8; ++j) {
        const int k = w * 256 + kgrp * 8 + j * 32;
        wIf[ct][j] = cvt8(WIb + row + k);
        wHf[ct][j] = cvt8(WHb + row + k);
      }
    }
  }

  // ---- epilogue: tid<128 -> (row rb2, 8 cols at c8) ----
  const int rb2 = tid >> 2;
  const int c8  = (tid & 3) * 8;
  float bias8[8];
#pragma unroll
  for (int j = 0; j < 8; ++j)
    bias8[j] = BI[l * HH + c0 + c8 + j] + BH[l * HH + c0 + c8 + j];

  for (int t = 0; t < LL; ++t) {
    const ull wantI = (((t >> rshift) & 1) ^ 1) ? TAGM : 0ULL;        // gen t
    const ull wantH = ((((t - 1) >> rshift) & 1) ^ 1) ? TAGM : 0ULL;  // gen t-1

    // ---------- flag gates (round-8/11/12-proven) ----------
    if (tid < 96) {
      const int g  = tid >> 5;
      const int Lt = tid & 31;
      if (g == 0) {
        if (t > 0)
          while (__hip_atomic_load(&pflag[l * TPL + Lt], __ATOMIC_RELAXED,
                                   __HIP_MEMORY_SCOPE_AGENT) < (unsigned)t)
            __builtin_amdgcn_s_sleep(2);
      } else if (g == 1) {
        if (l > 0)
          while (__hip_atomic_load(&pflag[(l - 1) * TPL + Lt], __ATOMIC_RELAXED,
                                   __HIP_MEMORY_SCOPE_AGENT) < (unsigned)(t + 1))
            __builtin_amdgcn_s_sleep(2);
      } else {
        if (l < NL - 1 && t > rsmask)
          while (__hip_atomic_load(&pflag[(l + 1) * TPL + Lt], __ATOMIC_RELAXED,
                                   __HIP_MEMORY_SCOPE_AGENT) < (unsigned)(t - rsmask))
            __builtin_amdgcn_s_sleep(2);
      }
    }
    __syncthreads();

    // ---------- cooperative coalesced staging: global -> LDS ----------
    // input operand: x (l==0) or h_{l-1} gen t
    if (l == 0) {
#pragma unroll
      for (int it = 0; it < 16; ++it) {
        const int q = it * 256 + tid;
        const int row = q >> 7, col = (q & 127) * 8;
        *reinterpret_cast<f16x8*>(&sIn[(size_t)row * SROW + col]) =
            cvt8(x + ((size_t)row * LL + t) * HH + col);
      }
    } else {
      const _Float16* src = hbuf + ((size_t)(l - 1) * (rsmask + 1) + (t & rsmask)) * BB * HH;
#pragma unroll
      for (int it = 0; it < 16; ++it) {
        const int q = it * 256 + tid;
        const int row = q >> 7, col = (q & 127) * 8;
        stage_q(&sIn[(size_t)row * SROW + col], src + (size_t)row * HH + col, wantI);
      }
    }
    // hidden operand: h0 (t==0) or own h gen t-1
    if (t == 0) {
#pragma unroll
      for (int it = 0; it < 16; ++it) {
        const int q = it * 256 + tid;
        const int row = q >> 7, col = (q & 127) * 8;
        *reinterpret_cast<f16x8*>(&sHid[(size_t)row * SROW + col]) =
            cvt8(h0 + ((size_t)l * BB + row) * HH + col);
      }
    } else {
      const _Float16* src = hbuf + ((size_t)l * (rsmask + 1) + ((t - 1) & rsmask)) * BB * HH;
#pragma unroll
      for (int it = 0; it < 16; ++it) {
        const int q = it * 256 + tid;
        const int row = q >> 7, col = (q & 127) * 8;
        stage_q(&sHid[(size_t)row * SROW + col], src + (size_t)row * HH + col, wantH);
      }
    }
    __syncthreads();

    // ---------- MFMA from LDS (wave = k-quarter, both operands) ----------
    f32x4 acc[2][2];
#pragma unroll
    for (int ct = 0; ct < 2; ++ct)
#pragma unroll
      for (int rt = 0; rt < 2; ++rt) acc[ct][rt] = (f32x4){0.f, 0.f, 0.f, 0.f};

#pragma unroll
    for (int j = 0; j < 8; ++j) {
      const int base = w * 256 + kgrp * 8 + j * 32;
      f16x8 ai0 = *reinterpret_cast<const f16x8*>(&sIn[(size_t)crow * SROW + base]);
      f16x8 ai1 = *reinterpret_cast<const f16x8*>(&sIn[(size_t)(16 + crow) * SROW + base]);
      f16x8 ah0 = *reinterpret_cast<const f16x8*>(&sHid[(size_t)crow * SROW + base]);
      f16x8 ah1 = *reinterpret_cast<const f16x8*>(&sHid[(size_t)(16 + crow) * SROW + base]);
#pragma unroll
      for (int ct = 0; ct < 2; ++ct) {
        acc[ct][0] = __builtin_amdgcn_mfma_f32_16x16x32_f16(ai0, wIf[ct][j], acc[ct][0], 0, 0, 0);
        acc[ct][1] = __builtin_amdgcn_mfma_f32_16x16x32_f16(ai1, wIf[ct][j], acc[ct][1], 0, 0, 0);
        acc[ct][0] = __builtin_amdgcn_mfma_f32_16x16x32_f16(ah0, wHf[ct][j], acc[ct][0], 0, 0, 0);
        acc[ct][1] = __builtin_amdgcn_mfma_f32_16x16x32_f16(ah1, wHf[ct][j], acc[ct][1], 0, 0, 0);
      }
    }

    // ---------- cross-wave k-reduce via LDS ----------
#pragma unroll
    for (int ct = 0; ct < 2; ++ct)
#pragma unroll
      for (int rt = 0; rt < 2; ++rt)
#pragma unroll
        for (int r = 0; r < 4; ++r)
          RED(w, rt, kgrp * 4 + r, ct * 16 + crow) = acc[ct][rt][r];
    __syncthreads();

    float v[8];
    if (tid < 128) {
#pragma unroll
      for (int j = 0; j < 8; ++j) {
        float s = bias8[j];
#pragma unroll
        for (int w2 = 0; w2 < 4; ++w2) s += RED(w2, rb2 >> 4, rb2 & 15, c8 + j);
        v[j] = tanhf(s);
      }
      union { _Float16 h[8]; ull u[2]; } pk;
#pragma unroll
      for (int j = 0; j < 8; ++j) pk.h[j] = (_Float16)v[j];
      const ull tg = (((t >> rshift) & 1) ^ 1) ? TAGM : 0ULL;
      pk.u[0] = (pk.u[0] & ~TAGM) | tg;
      pk.u[1] = (pk.u[1] & ~TAGM) | tg;
      const size_t off =
          ((size_t)l * (rsmask + 1) + (t & rsmask)) * BB * HH + (size_t)rb2 * HH + c0 + c8;
      __hip_atomic_store(reinterpret_cast<ull*>(hbuf + off), pk.u[0],
                         __ATOMIC_RELAXED, __HIP_MEMORY_SCOPE_AGENT);
      __hip_atomic_store(reinterpret_cast<ull*>(hbuf + off) + 1, pk.u[1],
                         __ATOMIC_RELAXED, __HIP_MEMORY_SCOPE_AGENT);
    }
    // Drain: all waves wait vmcnt(0) entering the barrier -> h at MALL.
    __syncthreads();

    // ---------- publish progress ----------
    if (tid == 0)
      __hip_atomic_store(&pflag[l * TPL + tile], (unsigned)(t + 1), __ATOMIC_RELAXED,
                         __HIP_MEMORY_SCOPE_AGENT);

    // ---------- out stores (off critical path) ----------
    if (tid < 128) {
      if (l == NL - 1) {
        f32x4 o0 = {v[0], v[1], v[2], v[3]}, o1 = {v[4], v[5], v[6], v[7]};
        float* po = out + ((size_t)rb2 * LL + t) * HH + c0 + c8;
        __builtin_nontemporal_store(o0, reinterpret_cast<f32x4*>(po));
        __builtin_nontemporal_store(o1, reinterpret_cast<f32x4*>(po + 4));
      }
      if (t == LL - 1) {
        f32x4 o0 = {v[0], v[1], v[2], v[3]}, o1 = {v[4], v[5], v[6], v[7]};
        float* pf = out + (size_t)BB * LL * HH + ((size_t)l * BB + rb2) * HH + c0 + c8;
        __builtin_nontemporal_store(o0, reinterpret_cast<f32x4*>(pf));
        __builtin_nontemporal_store(o1, reinterpret_cast<f32x4*>(pf + 4));
      }
    }
  }
#undef RED
}

extern "C" void kernel_launch(void* const* d_in, const int* in_sizes, int n_in,
                              void* d_out, int out_size, void* d_ws, size_t ws_size,
                              hipStream_t stream) {
  const float* x  = (const float*)d_in[0];
  const float* h0 = (const float*)d_in[1];
  const float* WI = (const float*)d_in[2];
  const float* BI = (const float*)d_in[3];
  const float* WH = (const float*)d_in[4];
  const float* BH = (const float*)d_in[5];
  float* out = (float*)d_out;

  // RS (slots per layer): prefer 512 = fully non-reused h stream.
  const size_t perSlot = (size_t)NL * BB * HH * sizeof(_Float16);  // 256 KB
  int rs = 512;
  while (rs > 8 && (size_t)rs * perSlot + 65536 > ws_size) rs >>= 1;
  int rshift = 0;
  while ((1 << rshift) < rs) ++rshift;

  _Float16* hbuf = (_Float16*)d_ws;
  unsigned* pflag = (unsigned*)((char*)d_ws + (size_t)rs * perSlot);

  const int smemBytes = 2 * 32 * SROW * (int)sizeof(_Float16) +
                        4 * 2 * 16 * 34 * (int)sizeof(float);   // 140800
  static int attrSet = 0;
  if (!attrSet) {
    hipFuncSetAttribute(reinterpret_cast<const void*>(rnn_persist),
                        hipFuncAttributeMaxDynamicSharedMemorySize, smemBytes);
    attrSet = 1;
  }

  hipMemsetAsync(pflag, 0, (size_t)NL * TPL * sizeof(unsigned), stream);
  rnn_persist<<<256, 256, smemBytes, stream>>>(x, h0, WI, BI, WH, BH, out, hbuf,
                                               pflag, rs - 1, rshift);
}

// Round 14
// 5734.461 us; speedup vs baseline: 1.3356x; 1.1494x over previous
//
#include <hip/hip_runtime.h>
#include <hip/hip_fp16.h>

#define BB 32
#define LL 512
#define HH 1024
#define NL 4
#define TPL 32   // blocks per layer
#define CPB 32   // cols per block
#define TAGM 0x0001000100010001ULL   // LSB of each f16 in an 8B quantum
#define SROW 1032  // LDS row stride in f16 (2064B): 2-way (free) bank aliasing

typedef unsigned long long ull;
typedef _Float16 f16x8 __attribute__((ext_vector_type(8)));
typedef float    f32x4 __attribute__((ext_vector_type(4)));

__device__ __forceinline__ f16x8 cvt8(const float* __restrict__ p) {
  f32x4 lo = *reinterpret_cast<const f32x4*>(p);
  f32x4 hi = *reinterpret_cast<const f32x4*>(p + 4);
  f16x8 r;
#pragma unroll
  for (int e = 0; e < 4; ++e) { r[e] = (_Float16)lo[e]; r[e + 4] = (_Float16)hi[e]; }
  return r;
}

__device__ __forceinline__ ull tag_bad(f16x8 v, ull want) {
  union { f16x8 v; ull u[2]; } c; c.v = v;
  return ((c.u[0] ^ want) | (c.u[1] ^ want)) & TAGM;
}

// Rare repair path (flag-gated so ~never taken): re-load one 16B quantum as
// two 8B relaxed agent atomics spinning on the tag (round-6-proven).
__device__ __forceinline__ f16x8 fix_q(const _Float16* __restrict__ gsrc, ull want) {
  const ull* p = reinterpret_cast<const ull*>(gsrc);
  union { ull u[2]; f16x8 v; } c;
  do {
    c.u[0] = __hip_atomic_load(p, __ATOMIC_RELAXED, __HIP_MEMORY_SCOPE_AGENT);
  } while ((c.u[0] ^ want) & TAGM);
  do {
    c.u[1] = __hip_atomic_load(p + 1, __ATOMIC_RELAXED, __HIP_MEMORY_SCOPE_AGENT);
  } while ((c.u[1] ^ want) & TAGM);
  return c.v;
}

// Persistent pipeline, 128 active blocks: layer = blockIdx&7 (XCD-locality
// heuristic only; flag gates + tags + MALL-spin repair keep correctness
// placement-independent). Block: 32 cols; weights in VGPRs (each wave holds
// both matrices' k-quarter). h transport: atomic stores to MALL; flag-gated
// COALESCED+BATCHED plain 16B loads (one latency exposure for all 32 quanta,
// 8 lanes/128B line -> L2 dedup) -> registers -> tag check -> LDS -> MFMA.
__global__ __launch_bounds__(256, 1) void rnn_persist(
    const float* __restrict__ x,   // [B][L][H] f32
    const float* __restrict__ h0,  // [NL][B][H] f32
    const float* __restrict__ WI,  // [NL][H][H] f32
    const float* __restrict__ BI,  // [NL][H]
    const float* __restrict__ WH,  // [NL][H][H] f32
    const float* __restrict__ BH,  // [NL][H]
    float* __restrict__ out,       // [B][L][H] f32 ++ hfinal [NL][B][H]
    _Float16* __restrict__ hbuf,   // [NL][RS][B][H] f16 (tagged), RS runtime
    unsigned* __restrict__ pflag,  // [NL][TPL]: t+1 after step t
    int rsmask, int rshift) {
  const int l = blockIdx.x & 7;
  if (l >= NL) return;
  const int tile = blockIdx.x >> 3;
  const int c0   = tile * CPB;
  const int tid  = threadIdx.x;
  const int w    = tid >> 6;          // wave -> k-quarter [256w, 256w+256)
  const int lane = tid & 63;
  const int crow = lane & 15;
  const int kgrp = lane >> 4;

  extern __shared__ char smem[];
  _Float16* sIn  = (_Float16*)smem;                     // [32][SROW]
  _Float16* sHid = sIn + 32 * SROW;                     // [32][SROW]
  float*    redp = (float*)(sHid + 32 * SROW);          // [4][2][16][34]
#define RED(W, RT, R, C) redp[((((W)*2 + (RT)) * 16 + (R)) * 34) + (C)]

  // ---- weight fragments -> registers (once): both matrices, own k-quarter ----
  f16x8 wIf[2][8], wHf[2][8];
  {
    const float* WIb = WI + (size_t)l * HH * HH;
    const float* WHb = WH + (size_t)l * HH * HH;
#pragma unroll
    for (int ct = 0; ct < 2; ++ct) {
      const size_t row = (size_t)(c0 + ct * 16 + crow) * HH;
#pragma unroll
      for (int j = 0; j < 8; ++j) {
        const int k = w * 256 + kgrp * 8 + j * 32;
        wIf[ct][j] = cvt8(WIb + row + k);
        wHf[ct][j] = cvt8(WHb + row + k);
      }
    }
  }

  // ---- staging geometry: thread's 16 quanta per operand, coalesced ----
  // q = it*256 + tid  ->  row = q>>7, col = (q&127)*8
  // ---- epilogue: tid<128 -> (row rb2, 8 cols at c8) ----
  const int rb2 = tid >> 2;
  const int c8  = (tid & 3) * 8;
  float bias8[8];
#pragma unroll
  for (int j = 0; j < 8; ++j)
    bias8[j] = BI[l * HH + c0 + c8 + j] + BH[l * HH + c0 + c8 + j];

  for (int t = 0; t < LL; ++t) {
    const ull wantI = (((t >> rshift) & 1) ^ 1) ? TAGM : 0ULL;        // gen t
    const ull wantH = ((((t - 1) >> rshift) & 1) ^ 1) ? TAGM : 0ULL;  // gen t-1

    // ---------- flag gates (round-8..13-proven) ----------
    if (tid < 96) {
      const int g  = tid >> 5;
      const int Lt = tid & 31;
      if (g == 0) {
        if (t > 0)
          while (__hip_atomic_load(&pflag[l * TPL + Lt], __ATOMIC_RELAXED,
                                   __HIP_MEMORY_SCOPE_AGENT) < (unsigned)t)
            __builtin_amdgcn_s_sleep(1);
      } else if (g == 1) {
        if (l > 0)
          while (__hip_atomic_load(&pflag[(l - 1) * TPL + Lt], __ATOMIC_RELAXED,
                                   __HIP_MEMORY_SCOPE_AGENT) < (unsigned)(t + 1))
            __builtin_amdgcn_s_sleep(1);
      } else {
        if (l < NL - 1 && t > rsmask)
          while (__hip_atomic_load(&pflag[(l + 1) * TPL + Lt], __ATOMIC_RELAXED,
                                   __HIP_MEMORY_SCOPE_AGENT) < (unsigned)(t - rsmask))
            __builtin_amdgcn_s_sleep(1);
      }
    }
    __syncthreads();

    // ---------- BATCHED coalesced staging: 32 x 16B loads, ONE exposure ----------
    f16x8 tin[16], thid[16];
    const _Float16* srcI =
        hbuf + ((size_t)(l - 1) * (rsmask + 1) + (t & rsmask)) * BB * HH;
    const _Float16* srcH =
        hbuf + ((size_t)l * (rsmask + 1) + ((t - 1) & rsmask)) * BB * HH;

    if (l == 0) {
#pragma unroll
      for (int it = 0; it < 16; ++it) {
        const int q = it * 256 + tid, row = q >> 7, col = (q & 127) * 8;
        tin[it] = cvt8(x + ((size_t)row * LL + t) * HH + col);
      }
    } else {
#pragma unroll
      for (int it = 0; it < 16; ++it) {
        const int q = it * 256 + tid, row = q >> 7, col = (q & 127) * 8;
        tin[it] = *reinterpret_cast<const f16x8*>(srcI + (size_t)row * HH + col);
      }
    }
    if (t == 0) {
#pragma unroll
      for (int it = 0; it < 16; ++it) {
        const int q = it * 256 + tid, row = q >> 7, col = (q & 127) * 8;
        thid[it] = cvt8(h0 + ((size_t)l * BB + row) * HH + col);
      }
    } else {
#pragma unroll
      for (int it = 0; it < 16; ++it) {
        const int q = it * 256 + tid, row = q >> 7, col = (q & 127) * 8;
        thid[it] = *reinterpret_cast<const f16x8*>(srcH + (size_t)row * HH + col);
      }
    }

    // ---------- batched tag check; per-quantum repair only on failure ----------
    if (l != 0 || t != 0) {
      ull badI = 0, badH = 0;
      if (l != 0) {
#pragma unroll
        for (int it = 0; it < 16; ++it) badI |= tag_bad(tin[it], wantI);
      }
      if (t != 0) {
#pragma unroll
        for (int it = 0; it < 16; ++it) badH |= tag_bad(thid[it], wantH);
      }
      if (badI) {
#pragma unroll
        for (int it = 0; it < 16; ++it) {
          const int q = it * 256 + tid, row = q >> 7, col = (q & 127) * 8;
          if (tag_bad(tin[it], wantI))
            tin[it] = fix_q(srcI + (size_t)row * HH + col, wantI);
        }
      }
      if (badH) {
#pragma unroll
        for (int it = 0; it < 16; ++it) {
          const int q = it * 256 + tid, row = q >> 7, col = (q & 127) * 8;
          if (tag_bad(thid[it], wantH))
            thid[it] = fix_q(srcH + (size_t)row * HH + col, wantH);
        }
      }
    }

    // ---------- registers -> LDS ----------
#pragma unroll
    for (int it = 0; it < 16; ++it) {
      const int q = it * 256 + tid, row = q >> 7, col = (q & 127) * 8;
      *reinterpret_cast<f16x8*>(&sIn [(size_t)row * SROW + col]) = tin[it];
      *reinterpret_cast<f16x8*>(&sHid[(size_t)row * SROW + col]) = thid[it];
    }
    __syncthreads();

    // ---------- MFMA from LDS (wave = k-quarter, both operands) ----------
    f32x4 acc[2][2];
#pragma unroll
    for (int ct = 0; ct < 2; ++ct)
#pragma unroll
      for (int rt = 0; rt < 2; ++rt) acc[ct][rt] = (f32x4){0.f, 0.f, 0.f, 0.f};

#pragma unroll
    for (int j = 0; j < 8; ++j) {
      const int base = w * 256 + kgrp * 8 + j * 32;
      f16x8 ai0 = *reinterpret_cast<const f16x8*>(&sIn [(size_t)crow * SROW + base]);
      f16x8 ai1 = *reinterpret_cast<const f16x8*>(&sIn [(size_t)(16 + crow) * SROW + base]);
      f16x8 ah0 = *reinterpret_cast<const f16x8*>(&sHid[(size_t)crow * SROW + base]);
      f16x8 ah1 = *reinterpret_cast<const f16x8*>(&sHid[(size_t)(16 + crow) * SROW + base]);
#pragma unroll
      for (int ct = 0; ct < 2; ++ct) {
        acc[ct][0] = __builtin_amdgcn_mfma_f32_16x16x32_f16(ai0, wIf[ct][j], acc[ct][0], 0, 0, 0);
        acc[ct][1] = __builtin_amdgcn_mfma_f32_16x16x32_f16(ai1, wIf[ct][j], acc[ct][1], 0, 0, 0);
        acc[ct][0] = __builtin_amdgcn_mfma_f32_16x16x32_f16(ah0, wHf[ct][j], acc[ct][0], 0, 0, 0);
        acc[ct][1] = __builtin_amdgcn_mfma_f32_16x16x32_f16(ah1, wHf[ct][j], acc[ct][1], 0, 0, 0);
      }
    }

    // ---------- cross-wave k-reduce via LDS ----------
#pragma unroll
    for (int ct = 0; ct < 2; ++ct)
#pragma unroll
      for (int rt = 0; rt < 2; ++rt)
#pragma unroll
        for (int r = 0; r < 4; ++r)
          RED(w, rt, kgrp * 4 + r, ct * 16 + crow) = acc[ct][rt][r];
    __syncthreads();

    float v[8];
    if (tid < 128) {
#pragma unroll
      for (int j = 0; j < 8; ++j) {
        float s = bias8[j];
#pragma unroll
        for (int w2 = 0; w2 < 4; ++w2) s += RED(w2, rb2 >> 4, rb2 & 15, c8 + j);
        v[j] = tanhf(s);
      }
      union { _Float16 h[8]; ull u[2]; } pk;
#pragma unroll
      for (int j = 0; j < 8; ++j) pk.h[j] = (_Float16)v[j];
      const ull tg = (((t >> rshift) & 1) ^ 1) ? TAGM : 0ULL;
      pk.u[0] = (pk.u[0] & ~TAGM) | tg;
      pk.u[1] = (pk.u[1] & ~TAGM) | tg;
      const size_t off =
          ((size_t)l * (rsmask + 1) + (t & rsmask)) * BB * HH + (size_t)rb2 * HH + c0 + c8;
      __hip_atomic_store(reinterpret_cast<ull*>(hbuf + off), pk.u[0],
                         __ATOMIC_RELAXED, __HIP_MEMORY_SCOPE_AGENT);
      __hip_atomic_store(reinterpret_cast<ull*>(hbuf + off) + 1, pk.u[1],
                         __ATOMIC_RELAXED, __HIP_MEMORY_SCOPE_AGENT);
    }
    // Drain: all waves wait vmcnt(0) entering the barrier -> h at MALL.
    __syncthreads();

    // ---------- publish progress ----------
    if (tid == 0)
      __hip_atomic_store(&pflag[l * TPL + tile], (unsigned)(t + 1), __ATOMIC_RELAXED,
                         __HIP_MEMORY_SCOPE_AGENT);

    // ---------- out stores (off critical path) ----------
    if (tid < 128) {
      if (l == NL - 1) {
        f32x4 o0 = {v[0], v[1], v[2], v[3]}, o1 = {v[4], v[5], v[6], v[7]};
        float* po = out + ((size_t)rb2 * LL + t) * HH + c0 + c8;
        __builtin_nontemporal_store(o0, reinterpret_cast<f32x4*>(po));
        __builtin_nontemporal_store(o1, reinterpret_cast<f32x4*>(po + 4));
      }
      if (t == LL - 1) {
        f32x4 o0 = {v[0], v[1], v[2], v[3]}, o1 = {v[4], v[5], v[6], v[7]};
        float* pf = out + (size_t)BB * LL * HH + ((size_t)l * BB + rb2) * HH + c0 + c8;
        __builtin_nontemporal_store(o0, reinterpret_cast<f32x4*>(pf));
        __builtin_nontemporal_store(o1, reinterpret_cast<f32x4*>(pf + 4));
      }
    }
  }
#undef RED
}

extern "C" void kernel_launch(void* const* d_in, const int* in_sizes, int n_in,
                              void* d_out, int out_size, void* d_ws, size_t ws_size,
                              hipStream_t stream) {
  const float* x  = (const float*)d_in[0];
  const float* h0 = (const float*)d_in[1];
  const float* WI = (const float*)d_in[2];
  const float* BI = (const float*)d_in[3];
  const float* WH = (const float*)d_in[4];
  const float* BH = (const float*)d_in[5];
  float* out = (float*)d_out;

  // RS (slots per layer): prefer 512 = fully non-reused h stream.
  const size_t perSlot = (size_t)NL * BB * HH * sizeof(_Float16);  // 256 KB
  int rs = 512;
  while (rs > 8 && (size_t)rs * perSlot + 65536 > ws_size) rs >>= 1;
  int rshift = 0;
  while ((1 << rshift) < rs) ++rshift;

  _Float16* hbuf = (_Float16*)d_ws;
  unsigned* pflag = (unsigned*)((char*)d_ws + (size_t)rs * perSlot);

  const int smemBytes = 2 * 32 * SROW * (int)sizeof(_Float16) +
                        4 * 2 * 16 * 34 * (int)sizeof(float);
  static int attrSet = 0;
  if (!attrSet) {
    hipFuncSetAttribute(reinterpret_cast<const void*>(rnn_persist),
                        hipFuncAttributeMaxDynamicSharedMemorySize, smemBytes);
    attrSet = 1;
  }

  hipMemsetAsync(pflag, 0, (size_t)NL * TPL * sizeof(unsigned), stream);
  rnn_persist<<<256, 256, smemBytes, stream>>>(x, h0, WI, BI, WH, BH, out, hbuf,
                                               pflag, rs - 1, rshift);
}

// Round 15
// 4308.729 us; speedup vs baseline: 1.7775x; 1.3309x over previous
//
#include <hip/hip_runtime.h>
#include <hip/hip_fp16.h>

#define BB 32
#define LL 512
#define HH 1024
#define NL 4
#define TPL 32   // blocks per layer
#define CPB 32   // cols per block
#define TAGM 0x0001000100010001ULL   // LSB of each f16; tags are per-f16 -> tear-proof
#define SROW 1032  // LDS row stride (f16)

typedef unsigned long long ull;
typedef _Float16 f16x8 __attribute__((ext_vector_type(8)));
typedef float    f32x4 __attribute__((ext_vector_type(4)));

__device__ __forceinline__ f16x8 cvt8(const float* __restrict__ p) {
  f32x4 lo = *reinterpret_cast<const f32x4*>(p);
  f32x4 hi = *reinterpret_cast<const f32x4*>(p + 4);
  f16x8 r;
#pragma unroll
  for (int e = 0; e < 4; ++e) { r[e] = (_Float16)lo[e]; r[e + 4] = (_Float16)hi[e]; }
  return r;
}

__device__ __forceinline__ ull tag_bad(f16x8 v, ull want) {
  union { f16x8 v; ull u[2]; } c; c.v = v;
  return ((c.u[0] ^ want) | (c.u[1] ^ want)) & TAGM;
}

// Guaranteed-terminating repair: 8B relaxed agent atomic (MALL) spin. The
// producer dual-stores the same address atomically, so the MALL copy always
// eventually carries valid tags (round-6-proven).
__device__ __forceinline__ f16x8 fix_q(const _Float16* __restrict__ gsrc, ull want) {
  const ull* p = reinterpret_cast<const ull*>(gsrc);
  union { ull u[2]; f16x8 v; } c;
  do {
    c.u[0] = __hip_atomic_load(p, __ATOMIC_RELAXED, __HIP_MEMORY_SCOPE_AGENT);
  } while ((c.u[0] ^ want) & TAGM);
  do {
    c.u[1] = __hip_atomic_load(p + 1, __ATOMIC_RELAXED, __HIP_MEMORY_SCOPE_AGENT);
  } while ((c.u[1] ^ want) & TAGM);
  return c.v;
}

// Persistent pipeline, 128 active blocks: layer = blockIdx&7 (XCD-locality
// heuristic only; tags + MALL fallback keep correctness placement-free).
// Hidden recurrence (critical path): dual-stored h, tag-validated local-L2
// reads, NO flags. Input edge (slack): flag-gated cold coalesced loads.
__global__ __launch_bounds__(256, 1) void rnn_persist(
    const float* __restrict__ x,   // [B][L][H] f32
    const float* __restrict__ h0,  // [NL][B][H] f32
    const float* __restrict__ WI,  // [NL][H][H] f32
    const float* __restrict__ BI,  // [NL][H]
    const float* __restrict__ WH,  // [NL][H][H] f32
    const float* __restrict__ BH,  // [NL][H]
    float* __restrict__ out,       // [B][L][H] f32 ++ hfinal [NL][B][H]
    _Float16* __restrict__ hbuf,   // [NL][RS][B][H] f16 (tagged)
    unsigned* __restrict__ pflag,  // [NL][TPL]: value v => step v-1 complete
    int rsmask, int rshift) {
  const int l = blockIdx.x & 7;
  if (l >= NL) return;
  const int tile = blockIdx.x >> 3;
  const int c0   = tile * CPB;
  const int tid  = threadIdx.x;
  const int w    = tid >> 6;          // wave -> k-quarter
  const int lane = tid & 63;
  const int crow = lane & 15;
  const int kgrp = lane >> 4;

  extern __shared__ char smem[];
  _Float16* sIn  = (_Float16*)smem;                     // [32][SROW]
  _Float16* sHid = sIn + 32 * SROW;                     // [32][SROW]
  float*    redp = (float*)(sHid + 32 * SROW);          // [4][2][16][34]
#define RED(W, RT, R, C) redp[((((W)*2 + (RT)) * 16 + (R)) * 34) + (C)]

  // ---- weight fragments -> registers (once): both matrices, own k-quarter ----
  f16x8 wIf[2][8], wHf[2][8];
  {
    const float* WIb = WI + (size_t)l * HH * HH;
    const float* WHb = WH + (size_t)l * HH * HH;
#pragma unroll
    for (int ct = 0; ct < 2; ++ct) {
      const size_t row = (size_t)(c0 + ct * 16 + crow) * HH;
#pragma unroll
      for (int j = 0; j < 8; ++j) {
        const int k = w * 256 + kgrp * 8 + j * 32;
        wIf[ct][j] = cvt8(WIb + row + k);
        wHf[ct][j] = cvt8(WHb + row + k);
      }
    }
  }

  const int rb2 = tid >> 2;
  const int c8  = (tid & 3) * 8;
  float bias8[8];
#pragma unroll
  for (int j = 0; j < 8; ++j)
    bias8[j] = BI[l * HH + c0 + c8 + j] + BH[l * HH + c0 + c8 + j];

  for (int t = 0; t < LL; ++t) {
    const ull wantI = (((t >> rshift) & 1) ^ 1) ? TAGM : 0ULL;        // gen t
    const ull wantH = ((((t - 1) >> rshift) & 1) ^ 1) ? TAGM : 0ULL;  // gen t-1

    // ---------- gates: input edge (l>0) + WAR (only if ring reuses) ----------
    if (tid < 64) {
      if (tid < 32) {
        if (l > 0)
          while (__hip_atomic_load(&pflag[(l - 1) * TPL + tid], __ATOMIC_RELAXED,
                                   __HIP_MEMORY_SCOPE_AGENT) < (unsigned)(t + 1))
            __builtin_amdgcn_s_sleep(1);
      } else {
        if (l < NL - 1 && t > rsmask)
          while (__hip_atomic_load(&pflag[(l + 1) * TPL + (tid - 32)], __ATOMIC_RELAXED,
                                   __HIP_MEMORY_SCOPE_AGENT) < (unsigned)(t - rsmask))
            __builtin_amdgcn_s_sleep(1);
      }
    }
    __syncthreads();   // barrier 1: also drains PREVIOUS step's h stores (vmcnt0)

    // publish previous step's completion (ordered by barrier-1's implicit drain)
    if (tid == 0 && t > 0)
      __hip_atomic_store(&pflag[l * TPL + tile], (unsigned)t, __ATOMIC_RELAXED,
                         __HIP_MEMORY_SCOPE_AGENT);

    // ---------- BATCHED coalesced staging ----------
    f16x8 tin[16], thid[16];
    const _Float16* srcI =
        hbuf + ((size_t)(l - 1) * (rsmask + 1) + (t & rsmask)) * BB * HH;
    const _Float16* srcH =
        hbuf + ((size_t)l * (rsmask + 1) + ((t - 1) & rsmask)) * BB * HH;

    if (l == 0) {
#pragma unroll
      for (int it = 0; it < 16; ++it) {
        const int q = it * 256 + tid, row = q >> 7, col = (q & 127) * 8;
        tin[it] = cvt8(x + ((size_t)row * LL + t) * HH + col);
      }
    } else {
#pragma unroll
      for (int it = 0; it < 16; ++it) {
        const int q = it * 256 + tid, row = q >> 7, col = (q & 127) * 8;
        tin[it] = *reinterpret_cast<const f16x8*>(srcI + (size_t)row * HH + col);
      }
    }
    if (t == 0) {
#pragma unroll
      for (int it = 0; it < 16; ++it) {
        const int q = it * 256 + tid, row = q >> 7, col = (q & 127) * 8;
        thid[it] = cvt8(h0 + ((size_t)l * BB + row) * HH + col);
      }
    } else {
#pragma unroll
      for (int it = 0; it < 16; ++it) {
        const int q = it * 256 + tid, row = q >> 7, col = (q & 127) * 8;
        thid[it] = *reinterpret_cast<const f16x8*>(srcH + (size_t)row * HH + col);
      }
    }

    // ---------- input: batched tag check; rare repair (flag-gated) ----------
    if (l != 0) {
      ull badI = 0;
#pragma unroll
      for (int it = 0; it < 16; ++it) badI |= tag_bad(tin[it], wantI);
      if (badI) {
#pragma unroll
        for (int it = 0; it < 16; ++it) {
          const int q = it * 256 + tid, row = q >> 7, col = (q & 127) * 8;
          if (tag_bad(tin[it], wantI))
            tin[it] = fix_q(srcI + (size_t)row * HH + col, wantI);
        }
      }
    }
    // ---------- hidden: tag-spin (UNGATED — this IS the sync). volatile
    // respin bypasses L1 (L2-served, same-XCD fresh); fix_q is the net. ----------
    if (t != 0) {
      ull badH = 0;
#pragma unroll
      for (int it = 0; it < 16; ++it) badH |= tag_bad(thid[it], wantH);
      if (badH) {
#pragma unroll
        for (int it = 0; it < 16; ++it) {
          const int q = it * 256 + tid, row = q >> 7, col = (q & 127) * 8;
          const _Float16* a = srcH + (size_t)row * HH + col;
          int tries = 0;
          while (tag_bad(thid[it], wantH)) {
            if (tries++ < 64) {
              const volatile ull* vp = reinterpret_cast<const volatile ull*>(a);
              union { ull u[2]; f16x8 v; } c;
              c.u[0] = vp[0]; c.u[1] = vp[1];
              thid[it] = c.v;
            } else {
              thid[it] = fix_q(a, wantH);   // terminates: producer dual-stores MALL
            }
          }
        }
      }
    }

    // ---------- registers -> LDS ----------
#pragma unroll
    for (int it = 0; it < 16; ++it) {
      const int q = it * 256 + tid, row = q >> 7, col = (q & 127) * 8;
      *reinterpret_cast<f16x8*>(&sIn [(size_t)row * SROW + col]) = tin[it];
      *reinterpret_cast<f16x8*>(&sHid[(size_t)row * SROW + col]) = thid[it];
    }
    __syncthreads();   // barrier 2

    // ---------- MFMA from LDS ----------
    f32x4 acc[2][2];
#pragma unroll
    for (int ct = 0; ct < 2; ++ct)
#pragma unroll
      for (int rt = 0; rt < 2; ++rt) acc[ct][rt] = (f32x4){0.f, 0.f, 0.f, 0.f};
#pragma unroll
    for (int j = 0; j < 8; ++j) {
      const int base = w * 256 + kgrp * 8 + j * 32;
      f16x8 ai0 = *reinterpret_cast<const f16x8*>(&sIn [(size_t)crow * SROW + base]);
      f16x8 ai1 = *reinterpret_cast<const f16x8*>(&sIn [(size_t)(16 + crow) * SROW + base]);
      f16x8 ah0 = *reinterpret_cast<const f16x8*>(&sHid[(size_t)crow * SROW + base]);
      f16x8 ah1 = *reinterpret_cast<const f16x8*>(&sHid[(size_t)(16 + crow) * SROW + base]);
#pragma unroll
      for (int ct = 0; ct < 2; ++ct) {
        acc[ct][0] = __builtin_amdgcn_mfma_f32_16x16x32_f16(ai0, wIf[ct][j], acc[ct][0], 0, 0, 0);
        acc[ct][1] = __builtin_amdgcn_mfma_f32_16x16x32_f16(ai1, wIf[ct][j], acc[ct][1], 0, 0, 0);
        acc[ct][0] = __builtin_amdgcn_mfma_f32_16x16x32_f16(ah0, wHf[ct][j], acc[ct][0], 0, 0, 0);
        acc[ct][1] = __builtin_amdgcn_mfma_f32_16x16x32_f16(ah1, wHf[ct][j], acc[ct][1], 0, 0, 0);
      }
    }

    // ---------- cross-wave k-reduce ----------
#pragma unroll
    for (int ct = 0; ct < 2; ++ct)
#pragma unroll
      for (int rt = 0; rt < 2; ++rt)
#pragma unroll
        for (int r = 0; r < 4; ++r)
          RED(w, rt, kgrp * 4 + r, ct * 16 + crow) = acc[ct][rt][r];
    __syncthreads();   // barrier 3

    float v[8];
    if (tid < 128) {
#pragma unroll
      for (int j = 0; j < 8; ++j) {
        float s = bias8[j];
#pragma unroll
        for (int w2 = 0; w2 < 4; ++w2) s += RED(w2, rb2 >> 4, rb2 & 15, c8 + j);
        v[j] = tanhf(s);
      }
      union { _Float16 h[8]; ull u[2]; f16x8 vv; } pk;
#pragma unroll
      for (int j = 0; j < 8; ++j) pk.h[j] = (_Float16)v[j];
      const ull tg = (((t >> rshift) & 1) ^ 1) ? TAGM : 0ULL;
      pk.u[0] = (pk.u[0] & ~TAGM) | tg;
      pk.u[1] = (pk.u[1] & ~TAGM) | tg;
      const size_t off =
          ((size_t)l * (rsmask + 1) + (t & rsmask)) * BB * HH + (size_t)rb2 * HH + c0 + c8;
      // dual store, SAME address: plain (dirty in local L2, serves same-XCD
      // tag-spins fast) + atomic write-through (MALL master for cross-XCD
      // consumers and fix_q termination). Same value -> any order/tear safe.
      *reinterpret_cast<f16x8*>(hbuf + off) = pk.vv;
      __hip_atomic_store(reinterpret_cast<ull*>(hbuf + off), pk.u[0],
                         __ATOMIC_RELAXED, __HIP_MEMORY_SCOPE_AGENT);
      __hip_atomic_store(reinterpret_cast<ull*>(hbuf + off) + 1, pk.u[1],
                         __ATOMIC_RELAXED, __HIP_MEMORY_SCOPE_AGENT);

      // out stores (fire-and-forget; drained by next iteration's barrier 1)
      if (l == NL - 1) {
        f32x4 o0 = {v[0], v[1], v[2], v[3]}, o1 = {v[4], v[5], v[6], v[7]};
        float* po = out + ((size_t)rb2 * LL + t) * HH + c0 + c8;
        __builtin_nontemporal_store(o0, reinterpret_cast<f32x4*>(po));
        __builtin_nontemporal_store(o1, reinterpret_cast<f32x4*>(po + 4));
      }
      if (t == LL - 1) {
        f32x4 o0 = {v[0], v[1], v[2], v[3]}, o1 = {v[4], v[5], v[6], v[7]};
        float* pf = out + (size_t)BB * LL * HH + ((size_t)l * BB + rb2) * HH + c0 + c8;
        __builtin_nontemporal_store(o0, reinterpret_cast<f32x4*>(pf));
        __builtin_nontemporal_store(o1, reinterpret_cast<f32x4*>(pf + 4));
      }
    }
  }

  // final publish: step LL-1 complete (ordered after drain)
  __syncthreads();
  if (tid == 0)
    __hip_atomic_store(&pflag[l * TPL + tile], (unsigned)LL, __ATOMIC_RELAXED,
                       __HIP_MEMORY_SCOPE_AGENT);
#undef RED
}

extern "C" void kernel_launch(void* const* d_in, const int* in_sizes, int n_in,
                              void* d_out, int out_size, void* d_ws, size_t ws_size,
                              hipStream_t stream) {
  const float* x  = (const float*)d_in[0];
  const float* h0 = (const float*)d_in[1];
  const float* WI = (const float*)d_in[2];
  const float* BI = (const float*)d_in[3];
  const float* WH = (const float*)d_in[4];
  const float* BH = (const float*)d_in[5];
  float* out = (float*)d_out;

  // RS (slots per layer): prefer 512 = fully write-once h stream.
  const size_t perSlot = (size_t)NL * BB * HH * sizeof(_Float16);  // 256 KB
  int rs = 512;
  while (rs > 8 && (size_t)rs * perSlot + 65536 > ws_size) rs >>= 1;
  int rshift = 0;
  while ((1 << rshift) < rs) ++rshift;

  _Float16* hbuf = (_Float16*)d_ws;
  unsigned* pflag = (unsigned*)((char*)d_ws + (size_t)rs * perSlot);

  const int smemBytes = 2 * 32 * SROW * (int)sizeof(_Float16) +
                        4 * 2 * 16 * 34 * (int)sizeof(float);
  static int attrSet = 0;
  if (!attrSet) {
    hipFuncSetAttribute(reinterpret_cast<const void*>(rnn_persist),
                        hipFuncAttributeMaxDynamicSharedMemorySize, smemBytes);
    attrSet = 1;
  }

  hipMemsetAsync(pflag, 0, (size_t)NL * TPL * sizeof(unsigned), stream);
  rnn_persist<<<256, 256, smemBytes, stream>>>(x, h0, WI, BI, WH, BH, out, hbuf,
                                               pflag, rs - 1, rshift);
}